// Round 20
// baseline (269.259 us; speedup 1.0000x reference)
//
#include <hip/hip_runtime.h>

typedef short bf16x8 __attribute__((ext_vector_type(8)));
typedef float f32x4 __attribute__((ext_vector_type(4)));
typedef unsigned int u32;
typedef unsigned short u16;

#define NIT 21
#define SMIN 1e-33f
#define LDSCOL 136   // padded k-stride in u16 (272B, 16B-aligned) — r16/r18-proven

static __device__ __forceinline__ u16 f2bf(float f) {   // RNE pack (validated r8/r14/r16/r18)
    u32 u = __float_as_uint(f);
    u = (u + 0x7fffu + ((u >> 16) & 1u)) >> 16;
    return (u16)u;
}
static __device__ __forceinline__ float bf2f(u16 h) {
    return __uint_as_float(((u32)h) << 16);
}

// MFMA Sinkhorn, ONE WAVE per 128x128 matrix — ZERO barriers.
// r18/r19 post-mortem: the 41 block-wide __syncthreads per matrix were ~50% of
// wall (2143 cy/phase measured vs ~900 cy of resource use); neither more TLP
// (r18) nor more ILP (r19) hides a barrier every wave stalls at. Here the
// producer and consumer of a/b are the SAME wave, so ordering is just
// compiler-inserted s_waitcnt lgkmcnt — no __syncthreads anywhere.
// Dataflow per matrix is r18's, scaled to 8 tile-sets per wave: af[8][4]
// (A-operand row fragments, 128 dw, MFMA-only -> AGPR-native, no shuttle
// cost), E^T LDS image (35.3KB -> 4 matrices/CU), a/b in 512B LDS. Phases:
// col = 8 independent 4-deep chains of v_mfma_f32_16x16x32_bf16 (they
// pipeline into each other's latency), row = same on af. Numerics identical
// to r18 (row-max shift, bf16 E, lazy rcp factors, m89 C/D layout, shared
// (lane,slot)->k map so HW k-permutation cancels).
__global__ __launch_bounds__(64, 1)
void sinkhorn_kernel(const float* __restrict__ in, float* __restrict__ out) {
    const int t  = threadIdx.x;
    const int lg = (t >> 4) & 3;   // k-group within wave
    const int ln = t & 15;         // m/n within tile
    const size_t mat = (size_t)blockIdx.x << 14;
    const float S = 36.067376022224085f;   // (1/0.04)*log2(e)

    __shared__ __align__(16) u16 Ecm[128 * LDSCOL];   // E^T: Ecm[n*LDSCOL+k] = E[k][n]
    __shared__ __align__(16) u16 a_lds[128];
    __shared__ __align__(16) u16 b_lds[128];

    bf16x8 af[8][4];   // af[s][c] = E[s*16+ln][c*32+lg*8 ..+7]  (MFMA-only use)

    // ---- init: per 16-row set: load, rowmax, E = bf16(2^((x-m)*S)); regs + E^T ----
#pragma unroll
    for (int s = 0; s < 8; ++s) {
        const int M = s * 16 + ln;
        const float* src = in + mat + (size_t)M * 128 + lg * 8;
        float v[4][8];
        float m = -3.4e38f;
#pragma unroll
        for (int c = 0; c < 4; ++c) {
            float4 f0 = *(const float4*)(src + c * 32);
            float4 f1 = *(const float4*)(src + c * 32 + 4);
            v[c][0] = f0.x; v[c][1] = f0.y; v[c][2] = f0.z; v[c][3] = f0.w;
            v[c][4] = f1.x; v[c][5] = f1.y; v[c][6] = f1.z; v[c][7] = f1.w;
#pragma unroll
            for (int j = 0; j < 8; ++j) m = fmaxf(m, v[c][j]);
        }
        m = fmaxf(m, __shfl_xor(m, 16));   // row M held by lanes {ln,+16,+32,+48}
        m = fmaxf(m, __shfl_xor(m, 32));
        const float nms = -m * S;
        float sum = 0.f;
#pragma unroll
        for (int c = 0; c < 4; ++c) {
            bf16x8 fr;
#pragma unroll
            for (int j = 0; j < 8; ++j) {
                float e = __builtin_amdgcn_exp2f(fmaf(v[c][j], S, nms));
                sum += e;
                fr[j] = (short)f2bf(e);
            }
            af[s][c] = fr;
#pragma unroll
            for (int j = 0; j < 8; ++j)     // one-time transposed scalar writes
                Ecm[(c * 32 + lg * 8 + j) * LDSCOL + M] = (u16)fr[j];
        }
        sum += __shfl_xor(sum, 16);
        sum += __shfl_xor(sum, 32);
        if (lg == 0) a_lds[M] = f2bf(__builtin_amdgcn_rcpf(fmaxf(sum, SMIN)));
    }
    // no barrier: same wave produces and consumes (lgkmcnt ordering)

    const f32x4 z4 = {0.f, 0.f, 0.f, 0.f};

#pragma unroll 1
    for (int it = 0; it < NIT; ++it) {
        // ---- col phase: colsum_n = sum_k a_k E_kn (A = a replicated; B from Ecm) ----
        bf16x8 aop[4];
#pragma unroll
        for (int c = 0; c < 4; ++c)
            aop[c] = *(const bf16x8*)&a_lds[c * 32 + lg * 8];
#pragma unroll
        for (int s = 0; s < 8; ++s) {
            const int N = s * 16 + ln;
            f32x4 acc = z4;
#pragma unroll
            for (int c = 0; c < 4; ++c) {
                bf16x8 bop = *(const bf16x8*)&Ecm[N * LDSCOL + c * 32 + lg * 8];
                acc = __builtin_amdgcn_mfma_f32_16x16x32_bf16(aop[c], bop, acc, 0, 0, 0);
            }
            if (lg == 0)   // D rows identical; lane holds col n=ln of its tile (m89)
                b_lds[N] = f2bf(__builtin_amdgcn_rcpf(fmaxf(acc[0], SMIN)));
        }

        // ---- row phase: rowsum_m = sum_k E_mk b_k  (B = b replicated) ----
        if (it < NIT - 1) {
            bf16x8 bop[4];
#pragma unroll
            for (int c = 0; c < 4; ++c)
                bop[c] = *(const bf16x8*)&b_lds[c * 32 + lg * 8];
#pragma unroll
            for (int s = 0; s < 8; ++s) {
                f32x4 r0 = z4;
#pragma unroll
                for (int c = 0; c < 4; ++c)
                    r0 = __builtin_amdgcn_mfma_f32_16x16x32_bf16(af[s][c], bop[c], r0, 0, 0, 0);
                if (ln == 0) {   // D cols identical; lane holds tile rows lg*4+r
#pragma unroll
                    for (int r = 0; r < 4; ++r)
                        a_lds[s * 16 + lg * 4 + r] =
                            f2bf(__builtin_amdgcn_rcpf(fmaxf(r0[r], SMIN)));
                }
            }
        }
    }

    // ---- epilogue: out = E * a_m * b_n ----
#pragma unroll
    for (int s = 0; s < 8; ++s) {
        const int M = s * 16 + ln;
        float* dst = out + mat + (size_t)M * 128 + lg * 8;
        const float av = bf2f(a_lds[M]);
#pragma unroll
        for (int c = 0; c < 4; ++c) {
            const bf16x8 e = af[s][c];
            const bf16x8 bop = *(const bf16x8*)&b_lds[c * 32 + lg * 8];
            float4 o0, o1;
            o0.x = bf2f((u16)e[0]) * av * bf2f((u16)bop[0]);
            o0.y = bf2f((u16)e[1]) * av * bf2f((u16)bop[1]);
            o0.z = bf2f((u16)e[2]) * av * bf2f((u16)bop[2]);
            o0.w = bf2f((u16)e[3]) * av * bf2f((u16)bop[3]);
            o1.x = bf2f((u16)e[4]) * av * bf2f((u16)bop[4]);
            o1.y = bf2f((u16)e[5]) * av * bf2f((u16)bop[5]);
            o1.z = bf2f((u16)e[6]) * av * bf2f((u16)bop[6]);
            o1.w = bf2f((u16)e[7]) * av * bf2f((u16)bop[7]);
            *(float4*)(dst + c * 32)     = o0;
            *(float4*)(dst + c * 32 + 4) = o1;
        }
    }
}

extern "C" void kernel_launch(void* const* d_in, const int* in_sizes, int n_in,
                              void* d_out, int out_size, void* d_ws, size_t ws_size,
                              hipStream_t stream) {
    (void)n_in; (void)d_ws; (void)ws_size; (void)out_size;
    const float* in  = (const float*)d_in[0];
    float*       out = (float*)d_out;
    const int n_mat = in_sizes[0] / (128 * 128);  // 4096
    sinkhorn_kernel<<<dim3(n_mat), dim3(64), 0, stream>>>(in, out);
}

// Round 21
// 146.778 us; speedup vs baseline: 1.8345x; 1.8345x over previous
//
#include <hip/hip_runtime.h>

typedef short bf16x8 __attribute__((ext_vector_type(8)));
typedef float f32x4 __attribute__((ext_vector_type(4)));
typedef unsigned int u32;
typedef unsigned short u16;

#define NIT 21
#define SMIN 1e-38f
#define CSH  140.0f    // constant exponent shift (r17-validated numerics)
#define LDSCOL 136     // padded row stride in u16 (272B, 16B-aligned)

static __device__ __forceinline__ u16 f2bf(float f) {   // RNE pack (validated r8/r14/r16/r18)
    u32 u = __float_as_uint(f);
    u = (u + 0x7fffu + ((u >> 16) & 1u)) >> 16;
    return (u16)u;
}
static __device__ __forceinline__ float bf2f(u16 h) {
    return __uint_as_float(((u32)h) << 16);
}

// MFMA Sinkhorn, 512 threads / 8 waves per 128x128 matrix, ALL fragments
// register-resident. r18 post-mortem: phase critical path was 4 Ecm b128
// reads -> 4-DEPENDENT-MFMA chain; the 35KB E^T image also capped LDS.
// Here each wave holds BOTH its 16-row tile (af, A-operand) and its 16-col
// tile (bf, B-operand) in registers (32 dw total, MFMA-only -> AGPR-native,
// no shuttles: r18 proved this for af). The E^T image shrinks to an 8.7KB
// 32-row staging chunk used 4x at init to transpose-build bf; loop phases
// read only the 256B a/b vectors (broadcast addresses -> conflict-free) and
// run two independent 2-deep MFMA chains. Init uses the r17-validated
// constant-shift E = 2^(x*S-140): single streaming pass, no rowmax, no
// 32-float buffer -> peak ~75 regs -> 3 blocks/CU (LDS no longer caps).
// m89 C/D layout; both mfma operands share the (lane,slot)->k map so any HW
// k-permutation cancels (r14/r16/r18-proven).
__global__ __launch_bounds__(512)
void sinkhorn_kernel(const float* __restrict__ in, float* __restrict__ out) {
    const int t  = threadIdx.x;
    const int w  = t >> 6;         // wave 0..7
    const int lg = (t >> 4) & 3;   // k-group within wave
    const int ln = t & 15;         // m/n within tile
    const int M  = w * 16 + ln;    // this lane's owned row (af) and col (bf)
    const size_t mat = (size_t)blockIdx.x << 14;
    const float S = 36.067376022224085f;   // (1/0.04)*log2(e)

    __shared__ __align__(16) u16 stage[32 * LDSCOL];   // 32-row transpose chunk (8.7KB)
    __shared__ __align__(16) u16 a_lds[128];
    __shared__ __align__(16) u16 b_lds[128];

    bf16x8 af[4];   // af[c] = E[M][c*32+lg*8 ..+7]          (A-operand)
    bf16x8 bf[4];   // bf[c] = E[c*32+lg*8 ..+7][M]          (B-operand)

    // ---- init: stream rows, E = bf16(2^(x*S - 140)), a = rcp(rowsum) ----
    {
        const float* src = in + mat + (size_t)M * 128 + lg * 8;
        float s = 0.f;
#pragma unroll
        for (int c = 0; c < 4; ++c) {
            float4 f0 = *(const float4*)(src + c * 32);
            float4 f1 = *(const float4*)(src + c * 32 + 4);
            float e0 = __builtin_amdgcn_exp2f(fmaf(f0.x, S, -CSH));
            float e1 = __builtin_amdgcn_exp2f(fmaf(f0.y, S, -CSH));
            float e2 = __builtin_amdgcn_exp2f(fmaf(f0.z, S, -CSH));
            float e3 = __builtin_amdgcn_exp2f(fmaf(f0.w, S, -CSH));
            float e4 = __builtin_amdgcn_exp2f(fmaf(f1.x, S, -CSH));
            float e5 = __builtin_amdgcn_exp2f(fmaf(f1.y, S, -CSH));
            float e6 = __builtin_amdgcn_exp2f(fmaf(f1.z, S, -CSH));
            float e7 = __builtin_amdgcn_exp2f(fmaf(f1.w, S, -CSH));
            s += ((e0 + e1) + (e2 + e3)) + ((e4 + e5) + (e6 + e7));
            bf16x8 fr;
            fr[0] = (short)f2bf(e0); fr[1] = (short)f2bf(e1);
            fr[2] = (short)f2bf(e2); fr[3] = (short)f2bf(e3);
            fr[4] = (short)f2bf(e4); fr[5] = (short)f2bf(e5);
            fr[6] = (short)f2bf(e6); fr[7] = (short)f2bf(e7);
            af[c] = fr;
        }
        s += __shfl_xor(s, 16);   // row M held by lanes {ln,+16,+32,+48}
        s += __shfl_xor(s, 32);
        if (lg == 0) a_lds[M] = f2bf(__builtin_amdgcn_rcpf(fmaxf(s, SMIN)));
    }

    // ---- build bf via 4 staged 32-row chunks (chunk q owned by waves 2q,2q+1) ----
#pragma unroll
    for (int q = 0; q < 4; ++q) {
        __syncthreads();                    // prior chunk's reads done / init visible
        if ((w >> 1) == q) {
            const int lr = ((w & 1) << 4) + ln;   // local row within chunk
#pragma unroll
            for (int c = 0; c < 4; ++c)
                *(bf16x8*)&stage[lr * LDSCOL + c * 32 + lg * 8] = af[c];  // vector writes
        }
        __syncthreads();
        bf16x8 fr;
#pragma unroll
        for (int j = 0; j < 8; ++j)         // k = q*32 + lg*8 + j, col = M
            fr[j] = (short)stage[(lg * 8 + j) * LDSCOL + M];
        bf[q] = fr;
    }
    __syncthreads();

    const f32x4 z4 = {0.f, 0.f, 0.f, 0.f};

#pragma unroll 1
    for (int it = 0; it < NIT; ++it) {
        // ---- col phase: colsum_n = sum_k a_k E_kn; two independent 2-deep chains ----
        {
            bf16x8 a0 = *(const bf16x8*)&a_lds[lg * 8];          // broadcast reads (lg-only addr)
            bf16x8 a1 = *(const bf16x8*)&a_lds[32 + lg * 8];
            bf16x8 a2 = *(const bf16x8*)&a_lds[64 + lg * 8];
            bf16x8 a3 = *(const bf16x8*)&a_lds[96 + lg * 8];
            f32x4 acc0 = __builtin_amdgcn_mfma_f32_16x16x32_bf16(a0, bf[0], z4, 0, 0, 0);
            f32x4 acc1 = __builtin_amdgcn_mfma_f32_16x16x32_bf16(a1, bf[1], z4, 0, 0, 0);
            acc0 = __builtin_amdgcn_mfma_f32_16x16x32_bf16(a2, bf[2], acc0, 0, 0, 0);
            acc1 = __builtin_amdgcn_mfma_f32_16x16x32_bf16(a3, bf[3], acc1, 0, 0, 0);
            if (lg == 0) {   // D rows identical; lane holds col n=M (m89 layout)
                float v = acc0[0] + acc1[0];
                b_lds[M] = f2bf(__builtin_amdgcn_rcpf(fmaxf(v, SMIN)));
            }
        }
        __syncthreads();

        // ---- row phase: rowsum_m = sum_k E_mk b_k ----
        if (it < NIT - 1) {
            bf16x8 b0 = *(const bf16x8*)&b_lds[lg * 8];
            bf16x8 b1 = *(const bf16x8*)&b_lds[32 + lg * 8];
            bf16x8 b2 = *(const bf16x8*)&b_lds[64 + lg * 8];
            bf16x8 b3 = *(const bf16x8*)&b_lds[96 + lg * 8];
            f32x4 r0 = __builtin_amdgcn_mfma_f32_16x16x32_bf16(af[0], b0, z4, 0, 0, 0);
            f32x4 r1 = __builtin_amdgcn_mfma_f32_16x16x32_bf16(af[1], b1, z4, 0, 0, 0);
            r0 = __builtin_amdgcn_mfma_f32_16x16x32_bf16(af[2], b2, r0, 0, 0, 0);
            r1 = __builtin_amdgcn_mfma_f32_16x16x32_bf16(af[3], b3, r1, 0, 0, 0);
            if (ln == 0) {   // D cols identical; lane holds tile rows lg*4+r
#pragma unroll
                for (int r = 0; r < 4; ++r) {
                    float v = r0[r] + r1[r];
                    a_lds[w * 16 + lg * 4 + r] =
                        f2bf(__builtin_amdgcn_rcpf(fmaxf(v, SMIN)));
                }
            }
            __syncthreads();
        }
    }

    // ---- epilogue: out = E * a_m * b_n ----
    {
        float* dst = out + mat + (size_t)M * 128 + lg * 8;
        const float av = bf2f(a_lds[M]);
#pragma unroll
        for (int c = 0; c < 4; ++c) {
            const bf16x8 e = af[c];
            const bf16x8 bop = *(const bf16x8*)&b_lds[c * 32 + lg * 8];
            float4 o0, o1;
            o0.x = bf2f((u16)e[0]) * av * bf2f((u16)bop[0]);
            o0.y = bf2f((u16)e[1]) * av * bf2f((u16)bop[1]);
            o0.z = bf2f((u16)e[2]) * av * bf2f((u16)bop[2]);
            o0.w = bf2f((u16)e[3]) * av * bf2f((u16)bop[3]);
            o1.x = bf2f((u16)e[4]) * av * bf2f((u16)bop[4]);
            o1.y = bf2f((u16)e[5]) * av * bf2f((u16)bop[5]);
            o1.z = bf2f((u16)e[6]) * av * bf2f((u16)bop[6]);
            o1.w = bf2f((u16)e[7]) * av * bf2f((u16)bop[7]);
            *(float4*)(dst + c * 32)     = o0;
            *(float4*)(dst + c * 32 + 4) = o1;
        }
    }
}

extern "C" void kernel_launch(void* const* d_in, const int* in_sizes, int n_in,
                              void* d_out, int out_size, void* d_ws, size_t ws_size,
                              hipStream_t stream) {
    (void)n_in; (void)d_ws; (void)ws_size; (void)out_size;
    const float* in  = (const float*)d_in[0];
    float*       out = (float*)d_out;
    const int n_mat = in_sizes[0] / (128 * 128);  // 4096
    sinkhorn_kernel<<<dim3(n_mat), dim3(512), 0, stream>>>(in, out);
}